// Round 2
// baseline (281.469 us; speedup 1.0000x reference)
//
#include <hip/hip_runtime.h>
#include <math.h>

constexpr int Dn = 4096;     // C*H*W (row length)
constexpr int Bn = 4096;     // batch
constexpr int NCLS = 10;
constexpr int CH = 16;       // rows per chunk == waves per pass12 block
constexpr int NBLK0 = Bn / 256;         // 16 pass0 blocks
constexpr int MAXCH = Bn / CH + NCLS;   // 266 grid upper bound

// Workspace layout (float/int units). NO pre-zeroing needed:
// every slot is written exactly once by plain stores before being read
// (lbuf accumulation is LDS-local; P rows written once per chunk).
constexpr int OFF_CEB  = 0;      // 16 floats: per-block CE sums
constexpr int OFF_CNT  = 16;     // 16*10 ints: blkcnt[b][c]
constexpr int OFF_XS   = 176;    // 1 float (zeroed by pass0 block 0)
constexpr int OFF_DONE = 177;    // 1 int   (zeroed by pass0 block 0)
constexpr int OFF_ORDB = 192;    // 16*10*256 ints: ORDB[b][c][r]
constexpr int OFF_P    = 41216;  // partials: MAXCH * 4096 floats (16B aligned)

// ---------------------------------------------------------------- pass 0
// CE + argmax + block-local class lists. 16 blocks x 256. NO global atomics.
__global__ __launch_bounds__(256) void pass0_ce_order(
    const float* __restrict__ outputs, const int* __restrict__ y,
    float* __restrict__ ws)
{
    const int t = threadIdx.x;
    const int b = blockIdx.x;
    const int i = b * 256 + t;
    const int w = t >> 6, lane = t & 63;
    int* wsi = (int*)ws;

    __shared__ int hist[NCLS];
    __shared__ float sce[4];
    if (t < NCLS) hist[t] = 0;
    __syncthreads();

    const float* o = outputs + (size_t)i * NCLS;
    float m = o[0]; int am = 0;
    #pragma unroll
    for (int k = 1; k < NCLS; ++k) { float ok = o[k]; if (ok > m) { m = ok; am = k; } }
    float se = 0.f;
    #pragma unroll
    for (int k = 0; k < NCLS; ++k) se += expf(o[k] - m);
    float ce = m + logf(se) - o[y[i]];

    int rank = atomicAdd(&hist[am], 1);              // LDS atomic only
    wsi[OFF_ORDB + (b * NCLS + am) * 256 + rank] = i;

    #pragma unroll
    for (int off = 32; off; off >>= 1) ce += __shfl_down(ce, off, 64);
    if (lane == 0) sce[w] = ce;
    __syncthreads();

    if (t < NCLS) wsi[OFF_CNT + b * NCLS + t] = hist[t];
    if (t == 0) ws[OFF_CEB + b] = sce[0] + sce[1] + sce[2] + sce[3];
    if (b == 0 && t == 32) { ws[OFF_XS] = 0.f; wsi[OFF_DONE] = 0; }
}

// ---------------------------------------------------------------- pass 12
// Fused stats + accumulate, grad read ONCE. One chunk (<=16 same-class rows)
// per 1024-thread block, one row per wave. 16-wave combine goes through ONE
// 16 KB LDS accumulator via native ds_add_f32. Accumulator addresses
// XOR-swizzled by s=(lane>>3)&3 so component-wise f32 adds are 2-way
// (conflict-free) instead of 8-way on the 32 banks.
// __launch_bounds__(1024, 4): 4 waves/EU = 1 block/CU -> VGPR cap 128, so
// the 64-register row array v[16] stays in VGPRs. (Round-1 regression: the
// default heuristic capped at 40 VGPRs and spilled the row to scratch.)
__global__ __launch_bounds__(1024, 4) void pass12_fused(
    const float* __restrict__ grad, float* __restrict__ ws)
{
    const int* wsi = (const int*)ws;
    const int t = threadIdx.x, w = t >> 6, lane = t & 63;

    __shared__ int lcnt[NBLK0 * NCLS];   // blkcnt[b][c]
    __shared__ int tot[NCLS];
    __shared__ float lbuf[Dn];           // 16 KB chunk accumulator

    ((float4*)lbuf)[t] = make_float4(0.f, 0.f, 0.f, 0.f);
    if (t < NBLK0 * NCLS) lcnt[t] = wsi[OFF_CNT + t];
    __syncthreads();
    if (t < NCLS) {
        int sum = 0;
        #pragma unroll
        for (int bb = 0; bb < NBLK0; ++bb) sum += lcnt[bb * NCLS + t];
        tot[t] = sum;
    }
    __syncthreads();

    // chunk map: blockIdx.x -> (class c, global start s0, class count cnt)
    int c = -1, s0 = 0, cnt = 0;
    {
        int bidx = (int)blockIdx.x, acc = 0;
        #pragma unroll
        for (int k = 0; k < NCLS; ++k) {
            int n = tot[k];
            int nch = (n + CH - 1) / CH;
            if (c < 0 && bidx < acc + nch) { c = k; s0 = (bidx - acc) * CH; cnt = n; }
            acc += nch;
        }
    }
    if (c < 0) return;                   // uniform per block (no barriers after)
    const int m = min(CH, cnt - s0);
    const int s = (lane >> 3) & 3;       // bank-spread XOR swizzle

    if (w < m) {
        // map global rank r (within class c) -> source pass0 block + local pos
        int idx;
        {
            const int r = s0 + w;
            int pref = 0, src = 0, loc = 0;
            #pragma unroll
            for (int bb = 0; bb < NBLK0; ++bb) {
                int n = lcnt[bb * NCLS + c];
                if (r >= pref && r < pref + n) { src = bb; loc = r - pref; }
                pref += n;
            }
            idx = wsi[OFF_ORDB + (src * NCLS + c) * 256 + loc];
        }
        const float4* row = (const float4*)grad + (size_t)idx * (Dn / 4);
        float4 v[16];
        #pragma unroll
        for (int k = 0; k < 16; ++k) v[k] = row[k * 64 + lane];

        // wave min (butterfly)
        float mn = fminf(fminf(v[0].x, v[0].y), fminf(v[0].z, v[0].w));
        #pragma unroll
        for (int k = 1; k < 16; ++k)
            mn = fminf(mn, fminf(fminf(v[k].x, v[k].y), fminf(v[k].z, v[k].w)));
        #pragma unroll
        for (int off = 1; off < 64; off <<= 1)
            mn = fminf(mn, __shfl_xor(mn, off, 64));

        // wave sum of squares of (g - mn)
        float ss = 0.f;
        #pragma unroll
        for (int k = 0; k < 16; ++k) {
            float dx = v[k].x - mn, dy = v[k].y - mn;
            float dz = v[k].z - mn, dw = v[k].w - mn;
            ss += dx * dx + dy * dy + dz * dz + dw * dw;
        }
        #pragma unroll
        for (int off = 1; off < 64; off <<= 1)
            ss += __shfl_xor(ss, off, 64);

        const float a = 1.0f / sqrtf(ss);    // min-max range cancels under L2
        const float b = -mn * a;

        // element e = k*256 + 4*lane + comp lives at lbuf[e ^ s] (bijective
        // within each aligned quad since s<4). Per instruction the 8-lane
        // groups hit disjoint bank quartets -> 2-way aliasing (free).
        #pragma unroll
        for (int k = 0; k < 16; ++k) {
            const int bk = k * 256 + 4 * lane;
            atomicAdd(&lbuf[bk + (s ^ 0)], fmaf(v[k].x, a, b));
            atomicAdd(&lbuf[bk + (s ^ 1)], fmaf(v[k].y, a, b));
            atomicAdd(&lbuf[bk + (s ^ 2)], fmaf(v[k].z, a, b));
            atomicAdd(&lbuf[bk + (s ^ 3)], fmaf(v[k].w, a, b));
        }
    }
    __syncthreads();

    // un-swizzle (owner lane of quad t is t&63 -> same s formula) and store
    // the chunk partial row, fully coalesced across all 1024 threads.
    {
        float4 u = ((const float4*)lbuf)[t];
        const int st = (t >> 3) & 3;
        float a0 = u.x, a1 = u.y, a2 = u.z, a3 = u.w;
        if (st & 1) { float tm = a0; a0 = a1; a1 = tm; tm = a2; a2 = a3; a3 = tm; }
        if (st & 2) { float tm = a0; a0 = a2; a2 = tm; tm = a1; a1 = a3; a3 = tm; }
        float4* Pc = (float4*)(ws + OFF_P) + (size_t)blockIdx.x * (Dn / 4);
        Pc[t] = make_float4(a0, a1, a2, a3);
    }
}

// ---------------------------------------------------------------- pass 34
// Reduce chunk partials per class (~26 chunks/class, 4.4 MB total, mostly
// L2/L3-resident), square, sum; last block finalizes.
// 64-thread blocks, grid 640: spreads the latency-bound chunk loop over all
// 256 CUs (the old 160x256 packed 640 waves onto only 160 CUs).
__global__ __launch_bounds__(64) void pass34_final(
    float* __restrict__ ws, float* __restrict__ out)
{
    const int t = threadIdx.x;
    const int idx = blockIdx.x * 64 + t;     // 0 .. 40959
    const int c = idx >> 12;                 // class (uniform per block)
    const int j = idx & (Dn - 1);
    const int* wsi = (const int*)ws;

    __shared__ int tot[NCLS];
    if (t < NCLS) {
        int s = 0;
        #pragma unroll
        for (int bb = 0; bb < NBLK0; ++bb) s += wsi[OFF_CNT + bb * NCLS + t];
        tot[t] = s;
    }
    __syncthreads();

    int cs = 0, ce2 = 0;
    {
        int acc = 0;
        #pragma unroll
        for (int k = 0; k < NCLS; ++k) {
            int nch = (tot[k] + CH - 1) / CH;
            if (k == c) { cs = acc; ce2 = acc + nch; }
            acc += nch;
        }
    }

    const float* P = ws + OFF_P;
    float s = 0.f;
    int ch = cs;
    for (; ch + 4 <= ce2; ch += 4)
        s += P[(size_t)(ch + 0) * Dn + j] + P[(size_t)(ch + 1) * Dn + j]
           + P[(size_t)(ch + 2) * Dn + j] + P[(size_t)(ch + 3) * Dn + j];
    for (; ch < ce2; ++ch) s += P[(size_t)ch * Dn + j];
    float p = s * s;

    #pragma unroll
    for (int off = 32; off; off >>= 1) p += __shfl_down(p, off, 64);
    if (t == 0) {
        atomicAdd(&ws[OFF_XS], p);
        __threadfence();
        int ticket = atomicAdd(&((int*)ws)[OFF_DONE], 1);
        if (ticket == (NCLS * Dn / 64) - 1) {
            float xs = atomicAdd(&ws[OFF_XS], 0.0f);   // coherent read
            double n2 = 0.0;
            #pragma unroll
            for (int k = 0; k < NCLS; ++k) { double nc = (double)tot[k]; n2 += nc * nc; }
            double cesum = 0.0;
            #pragma unroll
            for (int k = 0; k < NBLK0; ++k) cesum += (double)ws[OFF_CEB + k];
            double xloss = (n2 - (double)xs) / (2.0 * (double)Bn);
            out[0] = (float)(cesum / (double)Bn + xloss);
        }
    }
}

extern "C" void kernel_launch(void* const* d_in, const int* in_sizes, int n_in,
                              void* d_out, int out_size, void* d_ws, size_t ws_size,
                              hipStream_t stream)
{
    const float* outputs = (const float*)d_in[0];   // [4096,10] f32
    const float* grad    = (const float*)d_in[1];   // [4096,1,64,64] f32
    const int*   y       = (const int*)d_in[2];     // [4096] i32
    float* ws  = (float*)d_ws;
    float* out = (float*)d_out;

    pass0_ce_order<<<NBLK0, 256, 0, stream>>>(outputs, y, ws);
    pass12_fused<<<MAXCH, 1024, 0, stream>>>(grad, ws);
    pass34_final<<<NCLS * Dn / 64, 64, 0, stream>>>(ws, out);
}

// Round 3
// 129.336 us; speedup vs baseline: 2.1763x; 2.1763x over previous
//
#include <hip/hip_runtime.h>
#include <math.h>

constexpr int Dn = 4096;     // C*H*W (row length)
constexpr int Bn = 4096;     // batch
constexpr int NCLS = 10;
constexpr int CH = 4;        // rows per chunk == waves per pass12 block
constexpr int NBLK0 = Bn / 256;         // 16 pass0 blocks
constexpr int MAXCH = Bn / CH + NCLS;   // 1034 grid upper bound

// Workspace layout (float/int units). NO pre-zeroing needed:
// every slot is written exactly once by plain stores before being read.
constexpr int OFF_CEB  = 0;      // 16 floats: per-block CE sums
constexpr int OFF_CNT  = 16;     // 16*10 ints: blkcnt[b][c]
constexpr int OFF_XS   = 176;    // 1 float (zeroed by pass0 block 0)
constexpr int OFF_DONE = 177;    // 1 int   (zeroed by pass0 block 0)
constexpr int OFF_ORDB = 192;    // 16*10*256 ints: ORDB[b][c][r]
constexpr int OFF_P    = 41216;  // partials: MAXCH * 4096 floats (16B aligned)

// ---------------------------------------------------------------- pass 0
// CE + argmax + block-local class lists. 16 blocks x 256. NO global atomics.
__global__ __launch_bounds__(256) void pass0_ce_order(
    const float* __restrict__ outputs, const int* __restrict__ y,
    float* __restrict__ ws)
{
    const int t = threadIdx.x;
    const int b = blockIdx.x;
    const int i = b * 256 + t;
    const int w = t >> 6, lane = t & 63;
    int* wsi = (int*)ws;

    __shared__ int hist[NCLS];
    __shared__ float sce[4];
    if (t < NCLS) hist[t] = 0;
    __syncthreads();

    const float* o = outputs + (size_t)i * NCLS;
    float m = o[0]; int am = 0;
    #pragma unroll
    for (int k = 1; k < NCLS; ++k) { float ok = o[k]; if (ok > m) { m = ok; am = k; } }
    float se = 0.f;
    #pragma unroll
    for (int k = 0; k < NCLS; ++k) se += expf(o[k] - m);
    float ce = m + logf(se) - o[y[i]];

    int rank = atomicAdd(&hist[am], 1);              // LDS atomic only
    wsi[OFF_ORDB + (b * NCLS + am) * 256 + rank] = i;

    #pragma unroll
    for (int off = 32; off; off >>= 1) ce += __shfl_down(ce, off, 64);
    if (lane == 0) sce[w] = ce;
    __syncthreads();

    if (t < NCLS) wsi[OFF_CNT + b * NCLS + t] = hist[t];
    if (t == 0) ws[OFF_CEB + b] = sce[0] + sce[1] + sce[2] + sce[3];
    if (b == 0 && t == 32) { ws[OFF_XS] = 0.f; wsi[OFF_DONE] = 0; }
}

// ---------------------------------------------------------------- pass 12
// Register-pressure-immune redesign: the row lives in LDS, never in a big
// VGPR array (rounds 1-2 proved the compiler won't keep 64 row-registers
// live in wide blocks -> scratch/reload at 186 us). 256 threads / 4 waves /
// CH=4 rows. Per wave: stream global->LDS folding min into scalars, reduce;
// one LDS re-read pass for ss (same arithmetic as the verified kernels),
// reduce; publish (a,b). One barrier, then a 256-thread combine applies
// per-row (a,b) from LDS and writes the chunk partial. No LDS atomics, no
// swizzle, all accesses linear b128 -> conflict-free. Peak live set ~1
// float4 + scalars. LDS 65 KB -> 2 blocks/CU = 8 waves/CU, 16 outstanding
// dwordx4/wave = ~128 KB in flight/CU >> Little's-law need at 6.3 TB/s.
__global__ __launch_bounds__(256) void pass12_fused(
    const float* __restrict__ grad, float* __restrict__ ws)
{
    const int* wsi = (const int*)ws;
    const int t = threadIdx.x, w = t >> 6, lane = t & 63;

    __shared__ int lcnt[NBLK0 * NCLS];   // blkcnt[b][c]
    __shared__ int tot[NCLS];
    __shared__ float rows[CH][Dn];       // 64 KB row staging
    __shared__ float a4[CH], b4[CH];

    if (t < NBLK0 * NCLS) lcnt[t] = wsi[OFF_CNT + t];
    __syncthreads();
    if (t < NCLS) {
        int s = 0;
        #pragma unroll
        for (int bb = 0; bb < NBLK0; ++bb) s += lcnt[bb * NCLS + t];
        tot[t] = s;
    }
    __syncthreads();

    // chunk map: blockIdx.x -> (class c, global start s0, class count cnt)
    int c = -1, s0 = 0, cnt = 0;
    {
        int bidx = (int)blockIdx.x, acc = 0;
        #pragma unroll
        for (int k = 0; k < NCLS; ++k) {
            int n = tot[k];
            int nch = (n + CH - 1) / CH;
            if (c < 0 && bidx < acc + nch) { c = k; s0 = (bidx - acc) * CH; cnt = n; }
            acc += nch;
        }
    }
    if (c < 0) return;                   // uniform per block
    const int m = min(CH, cnt - s0);

    float4* rw = (float4*)rows[w];
    if (w < m) {
        // map global rank r (within class c) -> source pass0 block + local pos
        int idx;
        {
            const int r = s0 + w;
            int pref = 0, src = 0, loc = 0;
            #pragma unroll
            for (int bb = 0; bb < NBLK0; ++bb) {
                int n = lcnt[bb * NCLS + c];
                if (r >= pref && r < pref + n) { src = bb; loc = r - pref; }
                pref += n;
            }
            idx = wsi[OFF_ORDB + (src * NCLS + c) * 256 + loc];
        }
        const float4* row = (const float4*)grad + (size_t)idx * (Dn / 4);

        // stage global -> LDS, folding min (value is in a transient reg)
        float mn = 3.4e38f;
        #pragma unroll
        for (int k = 0; k < 16; ++k) {
            float4 v = row[k * 64 + lane];
            rw[k * 64 + lane] = v;
            mn = fminf(mn, fminf(fminf(v.x, v.y), fminf(v.z, v.w)));
        }
        #pragma unroll
        for (int off = 1; off < 64; off <<= 1)
            mn = fminf(mn, __shfl_xor(mn, off, 64));

        // ss = sum (g - mn)^2, re-read own row from LDS (same-wave ordering)
        float ss = 0.f;
        #pragma unroll
        for (int k = 0; k < 16; ++k) {
            float4 v = rw[k * 64 + lane];
            float dx = v.x - mn, dy = v.y - mn;
            float dz = v.z - mn, dw = v.w - mn;
            ss += dx * dx + dy * dy + dz * dz + dw * dw;
        }
        #pragma unroll
        for (int off = 1; off < 64; off <<= 1)
            ss += __shfl_xor(ss, off, 64);

        if (lane == 0) {
            float a = 1.0f / sqrtf(ss);      // min-max range cancels under L2
            a4[w] = a; b4[w] = -mn * a;
        }
    } else {
        // zero unused row + coeffs so stale LDS (potential NaN bits) can't
        // leak through the combine
        const float4 z = make_float4(0.f, 0.f, 0.f, 0.f);
        #pragma unroll
        for (int k = 0; k < 16; ++k) rw[k * 64 + lane] = z;
        if (lane == 0) { a4[w] = 0.f; b4[w] = 0.f; }
    }
    __syncthreads();

    // combine: each thread sums 4 quads across the 4 rows with per-row (a,b)
    const float A0 = a4[0], B0 = b4[0], A1 = a4[1], B1 = b4[1];
    const float A2 = a4[2], B2 = b4[2], A3 = a4[3], B3 = b4[3];
    const float4* r0 = (const float4*)rows[0];
    const float4* r1 = (const float4*)rows[1];
    const float4* r2 = (const float4*)rows[2];
    const float4* r3 = (const float4*)rows[3];
    float4* Pc = (float4*)(ws + OFF_P) + (size_t)blockIdx.x * (Dn / 4);
    #pragma unroll
    for (int i = 0; i < 4; ++i) {
        const int q = t + 256 * i;
        float4 u0 = r0[q], u1 = r1[q], u2 = r2[q], u3 = r3[q];
        float4 o;
        o.x = fmaf(u0.x, A0, B0) + fmaf(u1.x, A1, B1)
            + fmaf(u2.x, A2, B2) + fmaf(u3.x, A3, B3);
        o.y = fmaf(u0.y, A0, B0) + fmaf(u1.y, A1, B1)
            + fmaf(u2.y, A2, B2) + fmaf(u3.y, A3, B3);
        o.z = fmaf(u0.z, A0, B0) + fmaf(u1.z, A1, B1)
            + fmaf(u2.z, A2, B2) + fmaf(u3.z, A3, B3);
        o.w = fmaf(u0.w, A0, B0) + fmaf(u1.w, A1, B1)
            + fmaf(u2.w, A2, B2) + fmaf(u3.w, A3, B3);
        Pc[q] = o;
    }
}

// ---------------------------------------------------------------- pass 34
// Reduce chunk partials per class (~103 chunks/class, 17 MB total), square,
// sum; last block finalizes. 64-thread blocks, grid 640: spreads the
// latency-bound chunk loop over all CUs; ~103 independent loads/thread of
// ILP keep BW up despite low TLP.
__global__ __launch_bounds__(64) void pass34_final(
    float* __restrict__ ws, float* __restrict__ out)
{
    const int t = threadIdx.x;
    const int idx = blockIdx.x * 64 + t;     // 0 .. 40959
    const int c = idx >> 12;                 // class (uniform per block)
    const int j = idx & (Dn - 1);
    const int* wsi = (const int*)ws;

    __shared__ int tot[NCLS];
    if (t < NCLS) {
        int s = 0;
        #pragma unroll
        for (int bb = 0; bb < NBLK0; ++bb) s += wsi[OFF_CNT + bb * NCLS + t];
        tot[t] = s;
    }
    __syncthreads();

    int cs = 0, ce2 = 0;
    {
        int acc = 0;
        #pragma unroll
        for (int k = 0; k < NCLS; ++k) {
            int nch = (tot[k] + CH - 1) / CH;
            if (k == c) { cs = acc; ce2 = acc + nch; }
            acc += nch;
        }
    }

    const float* P = ws + OFF_P;
    float s = 0.f;
    int ch = cs;
    for (; ch + 4 <= ce2; ch += 4)
        s += P[(size_t)(ch + 0) * Dn + j] + P[(size_t)(ch + 1) * Dn + j]
           + P[(size_t)(ch + 2) * Dn + j] + P[(size_t)(ch + 3) * Dn + j];
    for (; ch < ce2; ++ch) s += P[(size_t)ch * Dn + j];
    float p = s * s;

    #pragma unroll
    for (int off = 32; off; off >>= 1) p += __shfl_down(p, off, 64);
    if (t == 0) {
        atomicAdd(&ws[OFF_XS], p);
        __threadfence();
        int ticket = atomicAdd(&((int*)ws)[OFF_DONE], 1);
        if (ticket == (NCLS * Dn / 64) - 1) {
            float xs = atomicAdd(&ws[OFF_XS], 0.0f);   // coherent read
            double n2 = 0.0;
            #pragma unroll
            for (int k = 0; k < NCLS; ++k) { double nc = (double)tot[k]; n2 += nc * nc; }
            double cesum = 0.0;
            #pragma unroll
            for (int k = 0; k < NBLK0; ++k) cesum += (double)ws[OFF_CEB + k];
            double xloss = (n2 - (double)xs) / (2.0 * (double)Bn);
            out[0] = (float)(cesum / (double)Bn + xloss);
        }
    }
}

extern "C" void kernel_launch(void* const* d_in, const int* in_sizes, int n_in,
                              void* d_out, int out_size, void* d_ws, size_t ws_size,
                              hipStream_t stream)
{
    const float* outputs = (const float*)d_in[0];   // [4096,10] f32
    const float* grad    = (const float*)d_in[1];   // [4096,1,64,64] f32
    const int*   y       = (const int*)d_in[2];     // [4096] i32
    float* ws  = (float*)d_ws;
    float* out = (float*)d_out;

    pass0_ce_order<<<NBLK0, 256, 0, stream>>>(outputs, y, ws);
    pass12_fused<<<MAXCH, 256, 0, stream>>>(grad, ws);
    pass34_final<<<NCLS * Dn / 64, 64, 0, stream>>>(ws, out);
}